// Round 5
// baseline (605.520 us; speedup 1.0000x reference)
//
#include <hip/hip_runtime.h>

#define B_ 256
#define T_ 1024
#define E_ 32
#define H_ 128
#define NOBS_ 1048576
#define RPB 2                 // batch rows per LSTM block
#define NBLK (B_ / RPB)       // 128 blocks
#define NW 4                  // waves per block
#define THREADS (NW * 64)     // 256

#define LROWH 144             // h row stride in shorts (288B) -> 2-way banks max (free)
#define HBUF (RPB * LROWH)    // one h buffer (2 rows) in shorts

#define L2E 1.4426950408889634f

typedef __attribute__((ext_vector_type(8))) short bf16x8;
typedef __attribute__((ext_vector_type(4))) float f32x4;
typedef __attribute__((ext_vector_type(4))) int   i32x4;

// LDS-only barrier: drains LDS ops only; global loads/stores stay in flight.
#define LDS_BARRIER() asm volatile("s_waitcnt lgkmcnt(0)\n\ts_barrier" ::: "memory")

__device__ __forceinline__ short f2bf(float x) {
    unsigned u = __float_as_uint(x);
    unsigned r = u + 0x7FFFu + ((u >> 16) & 1u);   // RNE
    return (short)(r >> 16);
}

// ---------------- embedding kernel ----------------
__global__ void embed_kernel(const int* __restrict__ obs_ids,
                             const int* __restrict__ obs_slot,
                             const int* __restrict__ action_ids,
                             const int* __restrict__ is_action,
                             const float* __restrict__ action_emb,
                             const float* __restrict__ obs_emb,
                             float* __restrict__ embedded) {
    __shared__ float s_act[5 * E_];
    __shared__ float s_obs[11 * E_];
    for (int i = threadIdx.x; i < 5 * E_; i += blockDim.x) s_act[i] = action_emb[i];
    for (int i = threadIdx.x; i < 11 * E_; i += blockDim.x) s_obs[i] = obs_emb[i];
    __syncthreads();

    int s = blockIdx.x * blockDim.x + threadIdx.x;
    if (s >= B_ * T_) return;

    float acc[E_];
    if (is_action[s]) {
        int a = action_ids[s];
        #pragma unroll
        for (int e = 0; e < E_; e++) acc[e] = s_act[a * E_ + e];
    } else {
        #pragma unroll
        for (int e = 0; e < E_; e++) acc[e] = 0.0f;
        int lo = 0, hi = NOBS_;
        while (lo < hi) {
            int mid = (lo + hi) >> 1;
            if (obs_slot[mid] < s) lo = mid + 1; else hi = mid;
        }
        int j = lo;
        while (j < NOBS_ && obs_slot[j] == s) {
            int id = obs_ids[j];
            #pragma unroll
            for (int e = 0; e < E_; e++) acc[e] += s_obs[id * E_ + e];
            j++;
        }
    }
    float4* dst = (float4*)(embedded + (size_t)s * E_);
    #pragma unroll
    for (int q = 0; q < E_ / 4; q++) {
        float4 v; v.x = acc[4*q]; v.y = acc[4*q+1]; v.z = acc[4*q+2]; v.w = acc[4*q+3];
        dst[q] = v;
    }
}

// ---------------- LSTM kernel ----------------
// RPB=2, 4 waves x 64 lanes = 256 threads = 256 elements (2 rows x 128 cols):
// exactly ONE h-element per lane -> minimal transcendental issue.
// Wave w owns h-cols [32w, 32w+32) as two 16-col MFMA tiles (tsel=0,1).
// A-rows duplicate each batch row x8 ((lane&15)>>3), so C rows 4q..4q+3 all
// hold batch q>>1. Dedup bijection: lane l owns element
// (row l>>5, col 32w + 16*((l>>4)&1) + (l&15)) = acc[(l>>4)&1][gt][0].
// Weights pre-scaled by log2e (2*log2e for g-gate) -> raw exp2; bias rides in
// as MFMA C operand; paired-rcp sigmoid*tanh; one lgkm barrier per step.
__launch_bounds__(THREADS, 1)
__global__ void lstm_kernel(const float* __restrict__ embedded,
                            const int* __restrict__ lengths,
                            const float* __restrict__ W_ih,
                            const float* __restrict__ W_hh,
                            const float* __restrict__ b_ih,
                            const float* __restrict__ b_hh,
                            float* __restrict__ outputs,
                            float* __restrict__ h_out,
                            float* __restrict__ c_out) {
    __shared__ __align__(16) short h_lds[2 * HBUF];   // double-buffered [2][LROWH]

    const int tid  = threadIdx.x;
    const int lane = tid & 63;
    const int wave = tid >> 6;
    const int row0 = blockIdx.x * RPB;

    const int kgrp = (lane >> 4) * 8;              // k-slice within K=32 tile
    const int brow = (lane & 15) >> 3;             // A-operand batch row (dup x8)

    // dedup ownership
    const int tsel_own = (lane >> 4) & 1;
    const int g_own    = lane >> 5;
    const int col_own  = (wave << 5) + (tsel_own << 4) + (lane & 15);

    // ---- persistent weight fragments (B operand), scaled by log2e ----
    bf16x8 wfrag[2][4][5];
    f32x4  biasv[2][4];
    #pragma unroll
    for (int ts = 0; ts < 2; ts++) {
        const int colc = (wave << 5) + (ts << 4) + (lane & 15);
        #pragma unroll
        for (int gt = 0; gt < 4; gt++) {
            const float scale = (gt == 2) ? (2.0f * L2E) : L2E;
            int gcol = gt * H_ + colc;
            {
                const float* p = W_ih + (size_t)gcol * E_ + kgrp;
                bf16x8 v;
                #pragma unroll
                for (int j = 0; j < 8; j++) v[j] = f2bf(p[j] * scale);
                wfrag[ts][gt][0] = v;
            }
            #pragma unroll
            for (int kt = 1; kt < 5; kt++) {
                const float* q = W_hh + (size_t)gcol * H_ + (kt - 1) * 32 + kgrp;
                bf16x8 v;
                #pragma unroll
                for (int j = 0; j < 8; j++) v[j] = f2bf(q[j] * scale);
                wfrag[ts][gt][kt] = v;
            }
            float bv = (b_ih[gcol] + b_hh[gcol]) * scale;
            biasv[ts][gt] = (f32x4)(bv);
        }
    }

    const int len = lengths[row0 + g_own];
    float cr = 0.0f, hr = 0.0f;

    // x source for this lane's A-fragment row
    const float* xp = embedded + ((size_t)(row0 + brow) * T_) * E_ + kgrp;

    const int rbase = brow * LROWH + kgrp;         // A h-read base (shorts)
    const int wofs  = g_own * LROWH + col_own;     // h write slot (shorts)
    float* const out_base = outputs + (size_t)(row0 + g_own) * T_ * H_ + col_own;

    // zero both h buffers
    for (int i = tid; i < 2 * HBUF; i += THREADS) h_lds[i] = 0;
    __syncthreads();

    float4 xAlo = *(const float4*)(xp + 0 * E_);
    float4 xAhi = *(const float4*)(xp + 0 * E_ + 4);
    float4 xBlo = *(const float4*)(xp + 1 * E_);
    float4 xBhi = *(const float4*)(xp + 1 * E_ + 4);

    auto step = [&](int t, int RD, int WR, float4& xlo, float4& xhi, bool PF) {
        // A fragments for h from current buffer (<=2-way banks: free)
        bf16x8 ah[4];
        #pragma unroll
        for (int kt = 0; kt < 4; kt++)
            ah[kt] = *(const bf16x8*)&h_lds[RD + rbase + kt * 32];

        // pack current x -> bf16 A fragment (vmcnt wait lands here)
        int x0, x1, x2, x3;
        asm("v_cvt_pk_bf16_f32 %0, %1, %2" : "=v"(x0) : "v"(xlo.x), "v"(xlo.y));
        asm("v_cvt_pk_bf16_f32 %0, %1, %2" : "=v"(x1) : "v"(xlo.z), "v"(xlo.w));
        asm("v_cvt_pk_bf16_f32 %0, %1, %2" : "=v"(x2) : "v"(xhi.x), "v"(xhi.y));
        asm("v_cvt_pk_bf16_f32 %0, %1, %2" : "=v"(x3) : "v"(xhi.z), "v"(xhi.w));
        i32x4 xi; xi[0] = x0; xi[1] = x1; xi[2] = x2; xi[3] = x3;
        bf16x8 xa = __builtin_bit_cast(bf16x8, xi);

        // prefetch x(t+2) (in flight across the barrier)
        if (PF) {
            const float* xq = xp + (size_t)(t + 2) * E_;
            xlo = *(const float4*)(xq + 0);
            xhi = *(const float4*)(xq + 4);
        }

        // 40 MFMAs: x-part (8, no LDS dep) first to cover ds_read latency
        f32x4 acc0[4], acc1[4];
        #pragma unroll
        for (int gt = 0; gt < 4; gt++) {
            acc0[gt] = __builtin_amdgcn_mfma_f32_16x16x32_bf16(xa, wfrag[0][gt][0], biasv[0][gt], 0, 0, 0);
            acc1[gt] = __builtin_amdgcn_mfma_f32_16x16x32_bf16(xa, wfrag[1][gt][0], biasv[1][gt], 0, 0, 0);
        }
        #pragma unroll
        for (int kt = 0; kt < 4; kt++) {
            #pragma unroll
            for (int gt = 0; gt < 4; gt++) {
                acc0[gt] = __builtin_amdgcn_mfma_f32_16x16x32_bf16(ah[kt], wfrag[0][gt][kt + 1], acc0[gt], 0, 0, 0);
                acc1[gt] = __builtin_amdgcn_mfma_f32_16x16x32_bf16(ah[kt], wfrag[1][gt][kt + 1], acc1[gt], 0, 0, 0);
            }
        }

        // dense elementwise: ONE element per lane (select owned tile via cndmask)
        float a_i = tsel_own ? acc1[0][0] : acc0[0][0];
        float a_f = tsel_own ? acc1[1][0] : acc0[1][0];
        float a_g = tsel_own ? acc1[2][0] : acc0[2][0];
        float a_o = tsel_own ? acc1[3][0] : acc0[3][0];

        // paired-rcp: i*g = (Eg-1) / ((1+Ai)(Eg+1)); clamp exp2 arg <= 80 so any
        // den-overflow case has true product < 4e-15 (safe).
        float Ai = exp2f(-a_i);
        float Eg = exp2f(fminf(a_g, 80.0f));
        float ig = (Eg - 1.0f) * __builtin_amdgcn_rcpf((1.0f + Ai) * (Eg + 1.0f));
        float Af = exp2f(-a_f);
        float f_ = __builtin_amdgcn_rcpf(1.0f + Af);
        float c_new = fmaf(f_, cr, ig);
        float Ec = exp2f(fminf((2.0f * L2E) * c_new, 80.0f));
        float Ao = exp2f(-a_o);
        float h_new = (Ec - 1.0f) * __builtin_amdgcn_rcpf((1.0f + Ao) * (Ec + 1.0f));

        bool m = (t < len);
        cr = m ? c_new : cr;
        hr = m ? h_new : hr;
        out_base[(size_t)t * H_] = m ? h_new : 0.0f;   // fire-and-forget

        // write h back (bf16) to the other buffer
        int hb;
        asm("v_cvt_pk_bf16_f32 %0, %1, %2" : "=v"(hb) : "v"(hr), "v"(hr));
        h_lds[WR + wofs] = (short)hb;

        LDS_BARRIER();
    };

    for (int t = 0; t < T_ - 2; t += 2) {
        step(t,     0,    HBUF, xAlo, xAhi, true);
        step(t + 1, HBUF, 0,    xBlo, xBhi, true);
    }
    step(T_ - 2, 0,    HBUF, xAlo, xAhi, false);
    step(T_ - 1, HBUF, 0,    xBlo, xBhi, false);

    h_out[(size_t)(row0 + g_own) * H_ + col_own] = hr;
    c_out[(size_t)(row0 + g_own) * H_ + col_own] = cr;
}

extern "C" void kernel_launch(void* const* d_in, const int* in_sizes, int n_in,
                              void* d_out, int out_size, void* d_ws, size_t ws_size,
                              hipStream_t stream) {
    const int*   obs_ids       = (const int*)d_in[0];
    const int*   obs_slot      = (const int*)d_in[1];
    const int*   action_ids    = (const int*)d_in[2];
    const int*   is_action     = (const int*)d_in[3];
    const int*   input_lengths = (const int*)d_in[4];
    const float* action_emb    = (const float*)d_in[5];
    const float* obs_emb       = (const float*)d_in[6];
    const float* W_ih          = (const float*)d_in[7];
    const float* W_hh          = (const float*)d_in[8];
    const float* b_ih          = (const float*)d_in[9];
    const float* b_hh          = (const float*)d_in[10];

    float* out      = (float*)d_out;
    float* outputs  = out;                                   // [B,T,H]
    float* h_out    = out + (size_t)B_ * T_ * H_;            // [1,B,H]
    float* c_out    = h_out + (size_t)B_ * H_;               // [1,B,H]
    float* embedded = c_out + (size_t)B_ * H_;               // [B,T,E]

    hipLaunchKernelGGL(embed_kernel, dim3((B_ * T_ + 255) / 256), dim3(256), 0, stream,
                       obs_ids, obs_slot, action_ids, is_action, action_emb, obs_emb, embedded);

    hipLaunchKernelGGL(lstm_kernel, dim3(NBLK), dim3(THREADS), 0, stream,
                       embedded, input_lengths, W_ih, W_hh, b_ih, b_hh,
                       outputs, h_out, c_out);
}

// Round 6
// 487.856 us; speedup vs baseline: 1.2412x; 1.2412x over previous
//
#include <hip/hip_runtime.h>

#define B_ 256
#define T_ 1024
#define E_ 32
#define H_ 128
#define NOBS_ 1048576
#define RPB 4                 // batch rows per LSTM block
#define NBLK (B_ / RPB)       // 64
#define NW 8                  // waves per block
#define THREADS (NW * 64)     // 512

#define HROW 144              // bytes per h row in LDS (128 i8 + 16 pad)
#define HBUF (RPB * HROW)     // one h buffer = 576 B

#define L2E 1.4426950408889634f

typedef __attribute__((ext_vector_type(8))) short bf16x8;
typedef __attribute__((ext_vector_type(4))) float f32x4;
typedef __attribute__((ext_vector_type(4))) int   i32x4;

// LDS-only barrier: drains LDS ops only; global loads/stores stay in flight.
#define LDS_BARRIER() asm volatile("s_waitcnt lgkmcnt(0)\n\ts_barrier" ::: "memory")

__device__ __forceinline__ short f2bf(float x) {
    unsigned u = __float_as_uint(x);
    unsigned r = u + 0x7FFFu + ((u >> 16) & 1u);   // RNE
    return (short)(r >> 16);
}

// ---------------- embedding kernel ----------------
__global__ void embed_kernel(const int* __restrict__ obs_ids,
                             const int* __restrict__ obs_slot,
                             const int* __restrict__ action_ids,
                             const int* __restrict__ is_action,
                             const float* __restrict__ action_emb,
                             const float* __restrict__ obs_emb,
                             float* __restrict__ embedded) {
    __shared__ float s_act[5 * E_];
    __shared__ float s_obs[11 * E_];
    for (int i = threadIdx.x; i < 5 * E_; i += blockDim.x) s_act[i] = action_emb[i];
    for (int i = threadIdx.x; i < 11 * E_; i += blockDim.x) s_obs[i] = obs_emb[i];
    __syncthreads();

    int s = blockIdx.x * blockDim.x + threadIdx.x;
    if (s >= B_ * T_) return;

    float acc[E_];
    if (is_action[s]) {
        int a = action_ids[s];
        #pragma unroll
        for (int e = 0; e < E_; e++) acc[e] = s_act[a * E_ + e];
    } else {
        #pragma unroll
        for (int e = 0; e < E_; e++) acc[e] = 0.0f;
        int lo = 0, hi = NOBS_;
        while (lo < hi) {
            int mid = (lo + hi) >> 1;
            if (obs_slot[mid] < s) lo = mid + 1; else hi = mid;
        }
        int j = lo;
        while (j < NOBS_ && obs_slot[j] == s) {
            int id = obs_ids[j];
            #pragma unroll
            for (int e = 0; e < E_; e++) acc[e] += s_obs[id * E_ + e];
            j++;
        }
    }
    float4* dst = (float4*)(embedded + (size_t)s * E_);
    #pragma unroll
    for (int q = 0; q < E_ / 4; q++) {
        float4 v; v.x = acc[4*q]; v.y = acc[4*q+1]; v.z = acc[4*q+2]; v.w = acc[4*q+3];
        dst[q] = v;
    }
}

// ---------------- LSTM kernel ----------------
// 8 waves x RPB=4. Wave w owns gate cols {gt*128 + 16w .. +16} for gt=0..3.
// MFMA cost per CU per step: x-part bf16 16x16x32 (32 tiles, 155 cy) +
// h-part i8 16x16x64 (64 tiles, 326 cy) -- vs 776 cy all-bf16.
// h feedback is i8-quantized (abs err 0.004); W_hh i8 with per-column scale
// (rel err <=0.4%, same as bf16); gates accumulate in exact i32; dequant is
// one cvt+fma per gate. Elementwise: one element per lane (dedup via A-row
// duplication x4: C reg0 row = 4*(lane>>4) -> batch row lane>>4).
__launch_bounds__(THREADS, 2)
__global__ void lstm_kernel(const float* __restrict__ embedded,
                            const int* __restrict__ lengths,
                            const float* __restrict__ W_ih,
                            const float* __restrict__ W_hh,
                            const float* __restrict__ b_ih,
                            const float* __restrict__ b_hh,
                            float* __restrict__ outputs,
                            float* __restrict__ h_out,
                            float* __restrict__ c_out) {
    __shared__ __align__(16) char h_lds[2 * HBUF];   // double-buffered [4][HROW] i8

    const int tid  = threadIdx.x;
    const int lane = tid & 63;
    const int wave = tid >> 6;
    const int row0 = blockIdx.x * RPB;

    const int col16  = (wave << 4) + (lane & 15);  // this lane's gate/h column
    const int kgrp8  = (lane >> 4) * 8;            // bf16 A/B k-offset (K=32 tile)
    const int kgrp16 = (lane >> 4) * 16;           // i8 A/B k-offset (K=64 tile)
    const int brow   = (lane & 15) >> 2;           // A-operand batch row (dup x4)
    const int g_own  = lane >> 4;                  // batch row this lane OWNS

    // ---- x-part weights (bf16, scaled by log2e; 2*log2e for g-gate) ----
    bf16x8 wx[4];
    f32x4  biasv[4];
    // ---- h-part weights (i8, per-column scale) ----
    i32x4  wh[4][2];
    float  dq[4];
    #pragma unroll
    for (int gt = 0; gt < 4; gt++) {
        const float scale = (gt == 2) ? (2.0f * L2E) : L2E;
        const int gcol = gt * H_ + col16;
        {
            const float* p = W_ih + (size_t)gcol * E_ + kgrp8;
            bf16x8 v;
            #pragma unroll
            for (int j = 0; j < 8; j++) v[j] = f2bf(p[j] * scale);
            wx[gt] = v;
        }
        biasv[gt] = (f32x4)((b_ih[gcol] + b_hh[gcol]) * scale);

        const float* q = W_hh + (size_t)gcol * H_;
        float m = 0.0f;
        #pragma unroll
        for (int t2 = 0; t2 < 2; t2++)
            #pragma unroll
            for (int j = 0; j < 16; j++)
                m = fmaxf(m, fabsf(q[t2 * 64 + kgrp16 + j]));
        m = fmaxf(m, __shfl_xor(m, 16));   // other k-chunks of the same column
        m = fmaxf(m, __shfl_xor(m, 32));
        const float s = 127.0f / m;
        dq[gt] = scale * m * (1.0f / (127.0f * 127.0f));
        #pragma unroll
        for (int t2 = 0; t2 < 2; t2++) {
            i32x4 v;
            #pragma unroll
            for (int d = 0; d < 4; d++) {
                int word = 0;
                #pragma unroll
                for (int b2 = 0; b2 < 4; b2++) {
                    int qi = (int)rintf(q[t2 * 64 + kgrp16 + d * 4 + b2] * s);
                    word |= (qi & 0xFF) << (b2 * 8);
                }
                v[d] = word;
            }
            wh[gt][t2] = v;
        }
    }

    const int len = lengths[row0 + g_own];
    float cr = 0.0f, hr = 0.0f;

    // x source for this lane's A-fragment row
    const float* xp = embedded + ((size_t)(row0 + brow) * T_) * E_ + kgrp8;

    const int rbase = brow * HROW + kgrp16;        // i8 A-read base (bytes)
    const int wofs  = g_own * HROW + col16;        // h write slot (bytes)
    float* const out_base = outputs + (size_t)(row0 + g_own) * T_ * H_ + col16;

    // zero both h buffers (h0 = 0)
    for (int i = tid; i < 2 * HBUF; i += THREADS) h_lds[i] = 0;
    __syncthreads();

    float4 xAlo = *(const float4*)(xp + 0 * E_);
    float4 xAhi = *(const float4*)(xp + 0 * E_ + 4);
    float4 xBlo = *(const float4*)(xp + 1 * E_);
    float4 xBhi = *(const float4*)(xp + 1 * E_ + 4);

    auto step = [&](int t, int RD, int WR, float4& xlo, float4& xhi, bool PF) {
        // h A-fragments (i8), 2 K-tiles of 64
        i32x4 ah0 = *(const i32x4*)&h_lds[RD + rbase + 0 * 64];
        i32x4 ah1 = *(const i32x4*)&h_lds[RD + rbase + 1 * 64];

        // pack current x -> bf16 A fragment (vmcnt wait lands here)
        int x0, x1, x2, x3;
        asm("v_cvt_pk_bf16_f32 %0, %1, %2" : "=v"(x0) : "v"(xlo.x), "v"(xlo.y));
        asm("v_cvt_pk_bf16_f32 %0, %1, %2" : "=v"(x1) : "v"(xlo.z), "v"(xlo.w));
        asm("v_cvt_pk_bf16_f32 %0, %1, %2" : "=v"(x2) : "v"(xhi.x), "v"(xhi.y));
        asm("v_cvt_pk_bf16_f32 %0, %1, %2" : "=v"(x3) : "v"(xhi.z), "v"(xhi.w));
        i32x4 xi; xi[0] = x0; xi[1] = x1; xi[2] = x2; xi[3] = x3;
        bf16x8 xa = __builtin_bit_cast(bf16x8, xi);

        // prefetch x(t+2) (in flight across the barrier)
        if (PF) {
            const float* xq = xp + (size_t)(t + 2) * E_;
            xlo = *(const float4*)(xq + 0);
            xhi = *(const float4*)(xq + 4);
        }

        // x-part (bf16, bias as C) and h-part (i8, exact i32 accumulate)
        f32x4 accf[4];
        i32x4 acci[4];
        const i32x4 zero = (i32x4)0;
        #pragma unroll
        for (int gt = 0; gt < 4; gt++)
            accf[gt] = __builtin_amdgcn_mfma_f32_16x16x32_bf16(xa, wx[gt], biasv[gt], 0, 0, 0);
        #pragma unroll
        for (int gt = 0; gt < 4; gt++)
            acci[gt] = __builtin_amdgcn_mfma_i32_16x16x64_i8(ah0, wh[gt][0], zero, 0, 0, 0);
        #pragma unroll
        for (int gt = 0; gt < 4; gt++)
            acci[gt] = __builtin_amdgcn_mfma_i32_16x16x64_i8(ah1, wh[gt][1], acci[gt], 0, 0, 0);

        // dense elementwise: ONE element per lane (reg 0 = row 4*g_own -> batch g_own)
        float a_i = fmaf((float)acci[0][0], dq[0], accf[0][0]);
        float a_f = fmaf((float)acci[1][0], dq[1], accf[1][0]);
        float a_g = fmaf((float)acci[2][0], dq[2], accf[2][0]);
        float a_o = fmaf((float)acci[3][0], dq[3], accf[3][0]);

        // paired-rcp: i*g = (Eg-1)/((1+Ai)(Eg+1)); clamp exp2 arg so overflow-safe
        float Ai = exp2f(-a_i);
        float Eg = exp2f(fminf(a_g, 80.0f));
        float ig = (Eg - 1.0f) * __builtin_amdgcn_rcpf((1.0f + Ai) * (Eg + 1.0f));
        float Af = exp2f(-a_f);
        float f_ = __builtin_amdgcn_rcpf(1.0f + Af);
        float c_new = fmaf(f_, cr, ig);
        float Ec = exp2f(fminf((2.0f * L2E) * c_new, 80.0f));
        float Ao = exp2f(-a_o);
        float h_new = (Ec - 1.0f) * __builtin_amdgcn_rcpf((1.0f + Ao) * (Ec + 1.0f));

        bool m = (t < len);
        cr = m ? c_new : cr;
        hr = m ? h_new : hr;
        out_base[(size_t)t * H_] = m ? h_new : 0.0f;   // fire-and-forget

        // write h back quantized to i8 for next step's A fragments
        int qh = (int)rintf(hr * 127.0f);
        h_lds[WR + wofs] = (char)qh;

        LDS_BARRIER();
    };

    for (int t = 0; t < T_ - 2; t += 2) {
        step(t,     0,    HBUF, xAlo, xAhi, true);
        step(t + 1, HBUF, 0,    xBlo, xBhi, true);
    }
    step(T_ - 2, 0,    HBUF, xAlo, xAhi, false);
    step(T_ - 1, HBUF, 0,    xBlo, xBhi, false);

    h_out[(size_t)(row0 + g_own) * H_ + col16] = hr;
    c_out[(size_t)(row0 + g_own) * H_ + col16] = cr;
}

extern "C" void kernel_launch(void* const* d_in, const int* in_sizes, int n_in,
                              void* d_out, int out_size, void* d_ws, size_t ws_size,
                              hipStream_t stream) {
    const int*   obs_ids       = (const int*)d_in[0];
    const int*   obs_slot      = (const int*)d_in[1];
    const int*   action_ids    = (const int*)d_in[2];
    const int*   is_action     = (const int*)d_in[3];
    const int*   input_lengths = (const int*)d_in[4];
    const float* action_emb    = (const float*)d_in[5];
    const float* obs_emb       = (const float*)d_in[6];
    const float* W_ih          = (const float*)d_in[7];
    const float* W_hh          = (const float*)d_in[8];
    const float* b_ih          = (const float*)d_in[9];
    const float* b_hh          = (const float*)d_in[10];

    float* out      = (float*)d_out;
    float* outputs  = out;                                   // [B,T,H]
    float* h_out    = out + (size_t)B_ * T_ * H_;            // [1,B,H]
    float* c_out    = h_out + (size_t)B_ * H_;               // [1,B,H]
    float* embedded = c_out + (size_t)B_ * H_;               // [B,T,E]

    hipLaunchKernelGGL(embed_kernel, dim3((B_ * T_ + 255) / 256), dim3(256), 0, stream,
                       obs_ids, obs_slot, action_ids, is_action, action_emb, obs_emb, embedded);

    hipLaunchKernelGGL(lstm_kernel, dim3(NBLK), dim3(THREADS), 0, stream,
                       embedded, input_lengths, W_ih, W_hh, b_ih, b_hh,
                       outputs, h_out, c_out);
}

// Round 7
// 481.524 us; speedup vs baseline: 1.2575x; 1.0131x over previous
//
#include <hip/hip_runtime.h>

#define B_ 256
#define T_ 1024
#define E_ 32
#define H_ 128
#define NOBS_ 1048576
#define RPB 4                 // batch rows per LSTM block
#define NBLK (B_ / RPB)       // 64
#define NW 8                  // waves per block
#define THREADS (NW * 64)     // 512

#define HROW 144              // bytes per h row in LDS (128 i8 + 16 pad)
#define HBUF (RPB * HROW)     // one h buffer = 576 B

#define L2E 1.4426950408889634f

typedef __attribute__((ext_vector_type(8))) short bf16x8;
typedef __attribute__((ext_vector_type(4))) float f32x4;
typedef __attribute__((ext_vector_type(4))) int   i32x4;

// LDS-only barrier: drains LDS ops only; global loads/stores stay in flight.
#define LDS_BARRIER() asm volatile("s_waitcnt lgkmcnt(0)\n\ts_barrier" ::: "memory")

__device__ __forceinline__ short f2bf(float x) {
    unsigned u = __float_as_uint(x);
    unsigned r = u + 0x7FFFu + ((u >> 16) & 1u);   // RNE
    return (short)(r >> 16);
}

// ---------------- embedding kernel ----------------
// writes f32 embedded (required output) and, if xbf != nullptr, a bf16 copy
// for the LSTM's x A-fragments (one 16B load instead of two f32x4 + cvt).
__global__ void embed_kernel(const int* __restrict__ obs_ids,
                             const int* __restrict__ obs_slot,
                             const int* __restrict__ action_ids,
                             const int* __restrict__ is_action,
                             const float* __restrict__ action_emb,
                             const float* __restrict__ obs_emb,
                             float* __restrict__ embedded,
                             unsigned short* __restrict__ xbf) {
    __shared__ float s_act[5 * E_];
    __shared__ float s_obs[11 * E_];
    for (int i = threadIdx.x; i < 5 * E_; i += blockDim.x) s_act[i] = action_emb[i];
    for (int i = threadIdx.x; i < 11 * E_; i += blockDim.x) s_obs[i] = obs_emb[i];
    __syncthreads();

    int s = blockIdx.x * blockDim.x + threadIdx.x;
    if (s >= B_ * T_) return;

    float acc[E_];
    if (is_action[s]) {
        int a = action_ids[s];
        #pragma unroll
        for (int e = 0; e < E_; e++) acc[e] = s_act[a * E_ + e];
    } else {
        #pragma unroll
        for (int e = 0; e < E_; e++) acc[e] = 0.0f;
        int lo = 0, hi = NOBS_;
        while (lo < hi) {
            int mid = (lo + hi) >> 1;
            if (obs_slot[mid] < s) lo = mid + 1; else hi = mid;
        }
        int j = lo;
        while (j < NOBS_ && obs_slot[j] == s) {
            int id = obs_ids[j];
            #pragma unroll
            for (int e = 0; e < E_; e++) acc[e] += s_obs[id * E_ + e];
            j++;
        }
    }
    float4* dst = (float4*)(embedded + (size_t)s * E_);
    #pragma unroll
    for (int q = 0; q < E_ / 4; q++) {
        float4 v; v.x = acc[4*q]; v.y = acc[4*q+1]; v.z = acc[4*q+2]; v.w = acc[4*q+3];
        dst[q] = v;
    }
    if (xbf) {
        unsigned short tmp[E_];
        #pragma unroll
        for (int e = 0; e < E_; e++) tmp[e] = (unsigned short)f2bf(acc[e]);
        int4* d2 = (int4*)(xbf + (size_t)s * E_);
        #pragma unroll
        for (int q = 0; q < E_ / 8; q++) d2[q] = ((const int4*)tmp)[q];
    }
}

// ---------------- LSTM kernel ----------------
// 8 waves x RPB=4, one element per lane. h-part: i8 16x16x64 MFMA (exact i32
// accumulate, per-column W_hh scale). x-part accf(t+1) = bias + x(t+1)*W_ih is
// HOISTED: its MFMAs issue right after step t's h-MFMAs, so they execute in
// the matrix pipe while this wave runs step t's elementwise VALU.
template<bool BF16X>
__launch_bounds__(THREADS, 2)
__global__ void lstm_kernel(const float* __restrict__ embedded,
                            const unsigned short* __restrict__ xbf,
                            const int* __restrict__ lengths,
                            const float* __restrict__ W_ih,
                            const float* __restrict__ W_hh,
                            const float* __restrict__ b_ih,
                            const float* __restrict__ b_hh,
                            float* __restrict__ outputs,
                            float* __restrict__ h_out,
                            float* __restrict__ c_out) {
    __shared__ __align__(16) char h_lds[2 * HBUF];   // double-buffered [4][HROW] i8

    const int tid  = threadIdx.x;
    const int lane = tid & 63;
    const int wave = tid >> 6;
    const int row0 = blockIdx.x * RPB;

    const int col16  = (wave << 4) + (lane & 15);  // this lane's gate/h column
    const int kgrp8  = (lane >> 4) * 8;            // bf16 A/B k-offset (K=32 tile)
    const int kgrp16 = (lane >> 4) * 16;           // i8 A/B k-offset (K=64 tile)
    const int brow   = (lane & 15) >> 2;           // A-operand batch row (dup x4)
    const int g_own  = lane >> 4;                  // batch row this lane OWNS

    // ---- x-part weights (bf16, scaled by log2e; 2*log2e for g-gate) ----
    bf16x8 wx[4];
    f32x4  biasv[4];
    // ---- h-part weights (i8, per-column scale) ----
    i32x4  wh[4][2];
    float  dq[4];
    #pragma unroll
    for (int gt = 0; gt < 4; gt++) {
        const float scale = (gt == 2) ? (2.0f * L2E) : L2E;
        const int gcol = gt * H_ + col16;
        {
            const float* p = W_ih + (size_t)gcol * E_ + kgrp8;
            bf16x8 v;
            #pragma unroll
            for (int j = 0; j < 8; j++) v[j] = f2bf(p[j] * scale);
            wx[gt] = v;
        }
        biasv[gt] = (f32x4)((b_ih[gcol] + b_hh[gcol]) * scale);

        const float* q = W_hh + (size_t)gcol * H_;
        float m = 0.0f;
        #pragma unroll
        for (int t2 = 0; t2 < 2; t2++)
            #pragma unroll
            for (int j = 0; j < 16; j++)
                m = fmaxf(m, fabsf(q[t2 * 64 + kgrp16 + j]));
        m = fmaxf(m, __shfl_xor(m, 16));   // other k-chunks of the same column
        m = fmaxf(m, __shfl_xor(m, 32));
        const float s = 127.0f / m;
        dq[gt] = scale * m * (1.0f / (127.0f * 127.0f));
        #pragma unroll
        for (int t2 = 0; t2 < 2; t2++) {
            i32x4 v;
            #pragma unroll
            for (int d = 0; d < 4; d++) {
                int word = 0;
                #pragma unroll
                for (int b2 = 0; b2 < 4; b2++) {
                    int qi = (int)rintf(q[t2 * 64 + kgrp16 + d * 4 + b2] * s);
                    word |= (qi & 0xFF) << (b2 * 8);
                }
                v[d] = word;
            }
            wh[gt][t2] = v;
        }
    }

    const int len = lengths[row0 + g_own];
    float cr = 0.0f, hr = 0.0f;

    // x fragment source (bf16 path: 16B per step; f32 path: 2x16B + cvt)
    const unsigned short* xpb = xbf + ((size_t)(row0 + brow) * T_) * E_ + kgrp8;
    const float*          xpf = embedded + ((size_t)(row0 + brow) * T_) * E_ + kgrp8;

    const int rbase = brow * HROW + kgrp16;        // i8 A-read base (bytes)
    const int wofs  = g_own * HROW + col16;        // h write slot (bytes)
    float* const out_base = outputs + (size_t)(row0 + g_own) * T_ * H_ + col16;

    // zero both h buffers (h0 = 0)
    for (int i = tid; i < 2 * HBUF; i += THREADS) h_lds[i] = 0;
    __syncthreads();

    // ---- x fragment load/convert helpers ----
    int4 xfA, xfB;                 // raw 16B (bf16 path) or staging
    float4 flA, fhA, flB, fhB;     // f32 path staging
    auto loadx = [&](int t, int4& xi4, float4& fl, float4& fh) {
        if (BF16X) {
            xi4 = *(const int4*)(xpb + (size_t)t * E_);
        } else {
            fl = *(const float4*)(xpf + (size_t)t * E_);
            fh = *(const float4*)(xpf + (size_t)t * E_ + 4);
        }
    };
    auto mkfrag = [&](const int4& xi4, const float4& fl, const float4& fh) -> bf16x8 {
        if (BF16X) {
            return __builtin_bit_cast(bf16x8, xi4);
        } else {
            int x0, x1, x2, x3;
            asm("v_cvt_pk_bf16_f32 %0, %1, %2" : "=v"(x0) : "v"(fl.x), "v"(fl.y));
            asm("v_cvt_pk_bf16_f32 %0, %1, %2" : "=v"(x1) : "v"(fl.z), "v"(fl.w));
            asm("v_cvt_pk_bf16_f32 %0, %1, %2" : "=v"(x2) : "v"(fh.x), "v"(fh.y));
            asm("v_cvt_pk_bf16_f32 %0, %1, %2" : "=v"(x3) : "v"(fh.z), "v"(fh.w));
            i32x4 xi; xi[0] = x0; xi[1] = x1; xi[2] = x2; xi[3] = x3;
            return __builtin_bit_cast(bf16x8, xi);
        }
    };

    // prologue: x(0), x(1) in regs; accfA = bias + x(0)*W_ih
    loadx(0, xfA, flA, fhA);
    loadx(1, xfB, flB, fhB);
    f32x4 accfA[4], accfB[4];
    {
        bf16x8 xa = mkfrag(xfA, flA, fhA);
        #pragma unroll
        for (int gt = 0; gt < 4; gt++)
            accfA[gt] = __builtin_amdgcn_mfma_f32_16x16x32_bf16(xa, wx[gt], biasv[gt], 0, 0, 0);
    }

    // one step: uses accf_cur for elementwise; computes accf_nxt = bias + x(t+1)*W
    // (issued between h-MFMAs and elementwise so it overlaps the VALU phase);
    // prefetches x(t+2) into (xf_pf, fl_pf, fh_pf).
    auto step = [&](int t, int RD, int WR,
                    f32x4* accf_cur, f32x4* accf_nxt,
                    const int4& xf_nx, const float4& fl_nx, const float4& fh_nx,
                    int4& xf_pf, float4& fl_pf, float4& fh_pf,
                    bool PF1, bool PF2) {
        // h A-fragments (i8), 2 K-tiles of 64
        i32x4 ah0 = *(const i32x4*)&h_lds[RD + rbase + 0 * 64];
        i32x4 ah1 = *(const i32x4*)&h_lds[RD + rbase + 1 * 64];

        // h-part MFMAs (exact i32)
        i32x4 acci[4];
        const i32x4 zero = (i32x4)0;
        #pragma unroll
        for (int gt = 0; gt < 4; gt++)
            acci[gt] = __builtin_amdgcn_mfma_i32_16x16x64_i8(ah0, wh[gt][0], zero, 0, 0, 0);
        #pragma unroll
        for (int gt = 0; gt < 4; gt++)
            acci[gt] = __builtin_amdgcn_mfma_i32_16x16x64_i8(ah1, wh[gt][1], acci[gt], 0, 0, 0);

        // hoisted x-part for t+1: executes in matrix pipe during elementwise
        if (PF1) {
            bf16x8 xa = mkfrag(xf_nx, fl_nx, fh_nx);
            #pragma unroll
            for (int gt = 0; gt < 4; gt++)
                accf_nxt[gt] = __builtin_amdgcn_mfma_f32_16x16x32_bf16(xa, wx[gt], biasv[gt], 0, 0, 0);
        }
        // prefetch x(t+2) (in flight across the barrier)
        if (PF2) loadx(t + 2, xf_pf, fl_pf, fh_pf);

        // dense elementwise: ONE element per lane
        float a_i = fmaf((float)acci[0][0], dq[0], accf_cur[0][0]);
        float a_f = fmaf((float)acci[1][0], dq[1], accf_cur[1][0]);
        float a_g = fmaf((float)acci[2][0], dq[2], accf_cur[2][0]);
        float a_o = fmaf((float)acci[3][0], dq[3], accf_cur[3][0]);

        float Ai = exp2f(-a_i);
        float Eg = exp2f(fminf(a_g, 80.0f));
        float ig = (Eg - 1.0f) * __builtin_amdgcn_rcpf((1.0f + Ai) * (Eg + 1.0f));
        float Af = exp2f(-a_f);
        float f_ = __builtin_amdgcn_rcpf(1.0f + Af);
        float c_new = fmaf(f_, cr, ig);
        float Ec = exp2f(fminf((2.0f * L2E) * c_new, 80.0f));
        float Ao = exp2f(-a_o);
        float h_new = (Ec - 1.0f) * __builtin_amdgcn_rcpf((1.0f + Ao) * (Ec + 1.0f));

        bool m = (t < len);
        cr = m ? c_new : cr;
        hr = m ? h_new : hr;
        out_base[(size_t)t * H_] = m ? h_new : 0.0f;   // fire-and-forget

        // write h back quantized to i8 for next step's A fragments
        int qh = (int)rintf(hr * 127.0f);
        h_lds[WR + wofs] = (char)qh;

        LDS_BARRIER();
    };

    for (int t = 0; t < T_ - 2; t += 2) {
        step(t,     0,    HBUF, accfA, accfB, xfB, flB, fhB, xfA, flA, fhA, true, true);
        step(t + 1, HBUF, 0,    accfB, accfA, xfA, flA, fhA, xfB, flB, fhB, true, t + 3 < T_);
    }
    step(T_ - 2, 0,    HBUF, accfA, accfB, xfB, flB, fhB, xfA, flA, fhA, true,  false);
    step(T_ - 1, HBUF, 0,    accfB, accfA, xfA, flA, fhA, xfB, flB, fhB, false, false);

    h_out[(size_t)(row0 + g_own) * H_ + col16] = hr;
    c_out[(size_t)(row0 + g_own) * H_ + col16] = cr;
}

extern "C" void kernel_launch(void* const* d_in, const int* in_sizes, int n_in,
                              void* d_out, int out_size, void* d_ws, size_t ws_size,
                              hipStream_t stream) {
    const int*   obs_ids       = (const int*)d_in[0];
    const int*   obs_slot      = (const int*)d_in[1];
    const int*   action_ids    = (const int*)d_in[2];
    const int*   is_action     = (const int*)d_in[3];
    const int*   input_lengths = (const int*)d_in[4];
    const float* action_emb    = (const float*)d_in[5];
    const float* obs_emb       = (const float*)d_in[6];
    const float* W_ih          = (const float*)d_in[7];
    const float* W_hh          = (const float*)d_in[8];
    const float* b_ih          = (const float*)d_in[9];
    const float* b_hh          = (const float*)d_in[10];

    float* out      = (float*)d_out;
    float* outputs  = out;                                   // [B,T,H]
    float* h_out    = out + (size_t)B_ * T_ * H_;            // [1,B,H]
    float* c_out    = h_out + (size_t)B_ * H_;               // [1,B,H]
    float* embedded = c_out + (size_t)B_ * H_;               // [B,T,E]

    const size_t xbf_bytes = (size_t)B_ * T_ * E_ * sizeof(unsigned short);
    const bool use_bf16x = (ws_size >= xbf_bytes);
    unsigned short* xbf = use_bf16x ? (unsigned short*)d_ws : nullptr;

    hipLaunchKernelGGL(embed_kernel, dim3((B_ * T_ + 255) / 256), dim3(256), 0, stream,
                       obs_ids, obs_slot, action_ids, is_action, action_emb, obs_emb,
                       embedded, xbf);

    if (use_bf16x) {
        hipLaunchKernelGGL((lstm_kernel<true>), dim3(NBLK), dim3(THREADS), 0, stream,
                           embedded, xbf, input_lengths, W_ih, W_hh, b_ih, b_hh,
                           outputs, h_out, c_out);
    } else {
        hipLaunchKernelGGL((lstm_kernel<false>), dim3(NBLK), dim3(THREADS), 0, stream,
                           embedded, xbf, input_lengths, W_ih, W_hh, b_ih, b_hh,
                           outputs, h_out, c_out);
    }
}